// Round 6
// baseline (380.726 us; speedup 1.0000x reference)
//
#include <hip/hip_runtime.h>
#include <stdint.h>
#include <math.h>

typedef unsigned short u16;
typedef __bf16 bf16x8 __attribute__((ext_vector_type(8)));
typedef unsigned short u16x8 __attribute__((ext_vector_type(8)));
typedef unsigned short us4 __attribute__((ext_vector_type(4)));
typedef float f32x4 __attribute__((ext_vector_type(4)));

#define DEVI __device__ __forceinline__

constexpr int B_ = 8, N_ = 1024, D_ = 768, H_ = 12, DH_ = 64, DF_ = 1536;

// float -> bf16 bits, round-to-nearest-even (finite inputs only)
DEVI u16 f2bu(float f) {
  unsigned x = __builtin_bit_cast(unsigned, f);
  x += 0x7FFFu + ((x >> 16) & 1u);
  return (u16)(x >> 16);
}
DEVI float b2f(u16 u) { return __builtin_bit_cast(float, (unsigned)u << 16); }

DEVI bf16x8 ld_frag(const u16* p) {
  return __builtin_bit_cast(bf16x8, *(const u16x8*)p);
}

DEVI void gload_lds16(const u16* g, u16* l) {
  __builtin_amdgcn_global_load_lds(
      (const __attribute__((address_space(1))) void*)g,
      (__attribute__((address_space(3))) void*)l, 16, 0, 0);
}

// ---------------------------------------------------------------------------
// All fp32 -> bf16 converts in ONE launch (7 jobs).
struct CvtArgs {
  const float* src[7];
  u16* dst[7];
  int n4[7];
  int start[8];  // cumulative block starts
};
__global__ __launch_bounds__(256)
void cvt_all(CvtArgs a) {
  const int gb = blockIdx.x;
  int j = 0;
  while (gb >= a.start[j + 1]) ++j;
  const int i = (gb - a.start[j]) * 256 + threadIdx.x;
  if (i >= a.n4[j]) return;
  float4 v = ((const float4*)a.src[j])[i];
  ushort4 o;
  o.x = f2bu(v.x); o.y = f2bu(v.y); o.z = f2bu(v.z); o.w = f2bu(v.w);
  ((ushort4*)a.dst[j])[i] = o;
}

// ---------------------------------------------------------------------------
// Compress relation_mask (B,N,N,R fp32) + node_mask into bit-packed,
// head-separated, k-transposed words:
//   mp[((b*H + h)*(N/16) + kt)*N + q], bit j = "head h masked at k = kt*16+j".
__global__ __launch_bounds__(256)
void build_mask_packed(const float* __restrict__ rel, const int* __restrict__ nm,
                       u16* __restrict__ mp) {
  const int b = blockIdx.z, q0 = blockIdx.y * 16, k0 = blockIdx.x * 256;
  const int t = threadIdx.x;
  __shared__ u16 w12[16][256];
  const int key_ok = nm[(b << 10) + k0 + t];
  const float th = 1e-4f;
#pragma unroll 1
  for (int it = 0; it < 16; ++it) {
    unsigned bits;
    if (!key_ok) {
      bits = 0xFFFu;
    } else {
      const size_t idx = (((size_t)(b << 10) + q0 + it) << 10) + k0 + t;
      const float2* rp = (const float2*)(rel + idx * 10);
      float2 a0 = rp[0], a1 = rp[1], a2 = rp[2], a3 = rp[3], a4 = rp[4];
      bits  = (a0.x < th ? 1u : 0u)   | (a0.y < th ? 2u : 0u)
            | (a1.x < th ? 4u : 0u)   | (a1.y < th ? 8u : 0u)
            | (a2.x < th ? 16u : 0u)  | (a2.y < th ? 32u : 0u)
            | (a3.x < th ? 64u : 0u)  | (a3.y < th ? 128u : 0u)
            | (a4.x < th ? 256u : 0u) | (a4.y < th ? 512u : 0u);
    }
    w12[it][t ^ ((it & 7) << 1)] = (u16)bits;
  }
  __syncthreads();
  const int ql = t & 15, kt = t >> 4;
  unsigned wv[16];
#pragma unroll
  for (int j2 = 0; j2 < 8; ++j2) {
    const int e = (kt * 16 + j2 * 2) ^ ((ql & 7) << 1);
    wv[j2 * 2] = w12[ql][e];
    wv[j2 * 2 + 1] = w12[ql][e + 1];
  }
#pragma unroll
  for (int h = 0; h < 12; ++h) {
    unsigned word = 0;
#pragma unroll
    for (int j = 0; j < 16; ++j) word |= ((wv[j] >> h) & 1u) << j;
    mp[(((size_t)(b * H_ + h)) * (N_ / 16) + (k0 >> 4) + kt) * N_ + q0 + ql] = (u16)word;
  }
}

// ---------------------------------------------------------------------------
// 256x256-tile GEMM, C = A(Mx768) @ B(Nx768)^T. 8 waves (2M x 4N), BK=32,
// TRIPLE-buffered LDS (96 KB), counted s_waitcnt vmcnt(4) + raw s_barrier:
// exactly 4 global_load_lds issued per thread per K-tile (targeting tile t+2),
// so vmcnt(4) at tile end == "tile t+1 fully landed, t+2 still in flight".
// Both-sides XOR swizzle: 16B-granule g ^= (row>>2)&3 on stage-source & read.
// EPI 0: fused QKV split write (Q scaled 1/8) -> q(b,h,i,dh), k(b,h,i,dh),
//        vT(b,h,dh,i).  EPI 1: +bias, gelu -> bf16 row-major [M][N].
template<int EPI>
__global__ __launch_bounds__(512, 2)
void gemm256(const u16* __restrict__ A, const u16* __restrict__ Bm,
             const float* __restrict__ bia0, const float* __restrict__ bia1,
             const float* __restrict__ bia2,
             u16* __restrict__ o0, u16* __restrict__ o1, u16* __restrict__ o2,
             int N) {
  constexpr int K = 768, NT = 24;
  __shared__ u16 As[3][256 * 32];
  __shared__ u16 Bs[3][256 * 32];
  const int t = threadIdx.x;
  const int w = t >> 6, l = t & 63;
  const int li = l & 15, grp = l >> 4;
  const int wr = w >> 2, wc = w & 3;

  // bijective XCD chunk swizzle (grid % 8 == 0)
  const int nbx = N >> 8;
  const int nwg = gridDim.x;
  int id = blockIdx.x;
  id = (id & 7) * (nwg >> 3) + (id >> 3);
  const int by = id / nbx, bx = id - by * nbx;
  const int m0 = by * 256, n0 = bx * 256;

  const int srl = t >> 2;   // row within a 128-row issue
  const int sg = t & 3;     // dest 16B granule within the 64B row
  auto stA = [&](int buf, int kt) {
#pragma unroll
    for (int i = 0; i < 2; ++i) {
      const int rl = i * 128 + srl;
      const int gs = sg ^ ((rl >> 2) & 3);
      gload_lds16(A + (size_t)(m0 + rl) * K + kt * 32 + gs * 8,
                  &As[buf][i * 4096 + w * 512]);
    }
  };
  auto stB = [&](int buf, int kt) {
#pragma unroll
    for (int i = 0; i < 2; ++i) {
      const int rl = i * 128 + srl;
      const int gs = sg ^ ((rl >> 2) & 3);
      gload_lds16(Bm + (size_t)(n0 + rl) * K + kt * 32 + gs * 8,
                  &Bs[buf][i * 4096 + w * 512]);
    }
  };
  auto rdA = [&](int buf, int fm) -> bf16x8 {
    const int row = wr * 128 + fm * 16 + li;
    const int g = grp ^ ((row >> 2) & 3);
    return ld_frag(&As[buf][row * 32 + g * 8]);
  };
  auto rdB = [&](int buf, int n) -> bf16x8 {
    const int row = wc * 64 + n * 16 + li;
    const int g = grp ^ ((row >> 2) & 3);
    return ld_frag(&Bs[buf][row * 32 + g * 8]);
  };

  f32x4 acc[8][4] = {};

  // prologue: tiles 0 and 1 in flight; wait tile 0 (newest 4 = tile 1)
  stA(0, 0); stB(0, 0); stA(1, 1); stB(1, 1);
  asm volatile("s_waitcnt vmcnt(4)\n\ts_barrier" ::: "memory");

  for (int kt = 0; kt < NT; ++kt) {
    const int bt = kt % 3, b2 = (kt + 2) % 3;
    const bool pre = (kt + 2 < NT);
    if (pre) stA(b2, kt + 2);
    bf16x8 bfr[4], af[4];
#pragma unroll
    for (int n = 0; n < 4; ++n) bfr[n] = rdB(bt, n);
#pragma unroll
    for (int fm = 0; fm < 4; ++fm) af[fm] = rdA(bt, fm);
    __builtin_amdgcn_s_setprio(1);
#pragma unroll
    for (int fm = 0; fm < 4; ++fm)
#pragma unroll
      for (int n = 0; n < 4; ++n)
        acc[fm][n] = __builtin_amdgcn_mfma_f32_16x16x32_bf16(af[fm], bfr[n], acc[fm][n], 0, 0, 0);
    __builtin_amdgcn_s_setprio(0);
    if (pre) stB(b2, kt + 2);
#pragma unroll
    for (int fm = 0; fm < 4; ++fm) af[fm] = rdA(bt, fm + 4);
    __builtin_amdgcn_s_setprio(1);
#pragma unroll
    for (int fm = 0; fm < 4; ++fm)
#pragma unroll
      for (int n = 0; n < 4; ++n)
        acc[fm + 4][n] = __builtin_amdgcn_mfma_f32_16x16x32_bf16(af[fm], bfr[n], acc[fm + 4][n], 0, 0, 0);
    __builtin_amdgcn_s_setprio(0);
    if (pre) asm volatile("s_waitcnt vmcnt(4)\n\ts_barrier" ::: "memory");
    else     asm volatile("s_waitcnt vmcnt(0)\n\ts_barrier" ::: "memory");
  }

#pragma unroll
  for (int fm = 0; fm < 8; ++fm) {
#pragma unroll
    for (int n = 0; n < 4; ++n) {
      const int col = n0 + wc * 64 + n * 16 + li;
#pragma unroll
      for (int j = 0; j < 4; ++j) {
        const int row = m0 + wr * 128 + fm * 16 + grp * 4 + j;
        float v = acc[fm][n][j];
        if constexpr (EPI == 0) {
          const int b = row >> 10, i = row & (N_ - 1);
          if (col < D_) {
            v = (v + bia0[col]) * 0.125f;  // fold 1/sqrt(DH) into Q
            o0[(((size_t)(b * H_ + (col >> 6))) * N_ + i) * DH_ + (col & 63)] = f2bu(v);
          } else if (col < 2 * D_) {
            const int c = col - D_;
            v += bia1[c];
            o1[(((size_t)(b * H_ + (c >> 6))) * N_ + i) * DH_ + (c & 63)] = f2bu(v);
          } else {
            const int c = col - 2 * D_;
            v += bia2[c];
            o2[(((size_t)(b * H_ + (c >> 6))) * DH_ + (c & 63)) * N_ + i] = f2bu(v);
          }
        } else {  // EPI == 1: +bias, gelu(exact) -> bf16
          v += bia0[col];
          float gel = 0.5f * v * (1.0f + erff(v * 0.70710678118654752440f));
          o0[(size_t)row * N + col] = f2bu(gel);
        }
      }
    }
  }
}

// ---------------------------------------------------------------------------
// 128x128-tile 2-phase GEMM (kept for N=768 shapes).
// EPI: 2 = +bias +fp32 resid -> bf16;  4 = +bias +bf16 resid -> bf16
template<int EPI>
__global__ __launch_bounds__(256, 2)
void gemm_bt(const u16* __restrict__ A, const u16* __restrict__ Bm,
             const float* __restrict__ bias0,
             const float* __restrict__ residf, const u16* __restrict__ residb,
             u16* __restrict__ out0,
             int M, int N, int K) {
  __shared__ u16 As[2][128 * 32];
  __shared__ u16 Bs[2][128 * 32];
  const int t = threadIdx.x;
  const int w = t >> 6, l = t & 63;
  const int li = l & 15, grp = l >> 4;
  const int nwg = gridDim.x * gridDim.y;
  int id = blockIdx.y * gridDim.x + blockIdx.x;
  id = (id & 7) * (nwg >> 3) + (id >> 3);
  const int by = id / gridDim.x;
  const int bx = id - by * gridDim.x;
  const int n0 = bx * 128, m0 = by * 128;
  const int wr = w >> 1, wc = w & 1;

  f32x4 acc[4][4] = {};

  const int arow = w * 16 + (l >> 2);
  const int acol = (l & 3) * 8;
  const u16* Ag = A + (size_t)(m0 + arow) * K + acol;
  const u16* Bg = Bm + (size_t)(n0 + arow) * K + acol;

  auto stage = [&](int buf, int k0) {
    u16* Asw = &As[buf][(w * 16) * 32];
    u16* Bsw = &Bs[buf][(w * 16) * 32];
    gload_lds16(Ag + k0, Asw);
    gload_lds16(Ag + (size_t)64 * K + k0, Asw + 64 * 32);
    gload_lds16(Bg + k0, Bsw);
    gload_lds16(Bg + (size_t)64 * K + k0, Bsw + 64 * 32);
  };

  stage(0, 0);
  __syncthreads();
  int cur = 0;
  for (int k0 = 0; k0 < K; k0 += 32) {
    if (k0 + 32 < K) stage(cur ^ 1, k0 + 32);
    bf16x8 af[4], bfr[4];
#pragma unroll
    for (int m = 0; m < 4; ++m)
      af[m] = ld_frag(&As[cur][(wr * 64 + m * 16 + li) * 32 + grp * 8]);
#pragma unroll
    for (int n = 0; n < 4; ++n)
      bfr[n] = ld_frag(&Bs[cur][(wc * 64 + n * 16 + li) * 32 + grp * 8]);
#pragma unroll
    for (int m = 0; m < 4; ++m)
#pragma unroll
      for (int n = 0; n < 4; ++n)
        acc[m][n] = __builtin_amdgcn_mfma_f32_16x16x32_bf16(af[m], bfr[n], acc[m][n], 0, 0, 0);
    __syncthreads();
    cur ^= 1;
  }

#pragma unroll
  for (int m = 0; m < 4; ++m) {
#pragma unroll
    for (int n = 0; n < 4; ++n) {
#pragma unroll
      for (int j = 0; j < 4; ++j) {
        const int row = m0 + wr * 64 + m * 16 + grp * 4 + j;
        const int col = n0 + wc * 64 + n * 16 + li;
        float v = acc[m][n][j];
        if constexpr (EPI == 2) {
          v += bias0[col] + residf[(size_t)row * N + col];
          out0[(size_t)row * N + col] = f2bu(v);
        } else {  // EPI == 4
          v += bias0[col] + b2f(residb[(size_t)row * N + col]);
          out0[(size_t)row * N + col] = f2bu(v);
        }
      }
    }
  }
}

// ---------------------------------------------------------------------------
// Flash attention (unchanged from round 5).
__global__ __launch_bounds__(512, 4)
void attn(const u16* __restrict__ q, const u16* __restrict__ k, const u16* __restrict__ vT,
          const u16* __restrict__ mp, u16* __restrict__ outp) {
  const int nwg = gridDim.x;
  const int p = blockIdx.x;
  const int lid = (p & 7) * (nwg >> 3) + (p >> 3);
  const int bh_i = lid >> 3;
  const int qblk = lid & 7;
  const int b = bh_i / H_, h = bh_i - (bh_i / H_) * H_;
  const int w = threadIdx.x >> 6, l = threadIdx.x & 63;
  const int li = l & 15, grp = l >> 4;
  const int qw = qblk * 128 + w * 16;
  const size_t bh = (size_t)bh_i;

  __shared__ u16 Kt[2][64 * 64];
  __shared__ u16 Vt[2][64 * 64];
  __shared__ u16 P[8][16 * 64];

  const u16* kbase = k + bh * N_ * DH_;
  const u16* vbase = vT + bh * DH_ * N_;

  const int srow_off = l >> 3;
  const int sg = l & 7;
  const int r0 = w * 8;
  auto stageK = [&](int buf, int kj0) {
    const int row = r0 + srow_off;
    const int gp = sg ^ (row & 7);
    gload_lds16(kbase + (size_t)(kj0 + row) * DH_ + gp * 8, &Kt[buf][r0 * 64]);
  };
  auto stageV = [&](int buf, int kj0) {
    const int row = r0 + srow_off;
    const int gp = sg ^ (row & 7);
    gload_lds16(vbase + (size_t)row * N_ + kj0 + gp * 8, &Vt[buf][r0 * 64]);
  };

  const u16* qp = q + (bh * N_ + qw) * DH_;
  const bf16x8 bq0 = ld_frag(qp + li * DH_ + grp * 8);
  const bf16x8 bq1 = ld_frag(qp + li * DH_ + 32 + grp * 8);

  f32x4 accO[4] = {};
  float m = -INFINITY, lsum = 0.f;

  u16* Pw = &P[w][0];
  const int sw = (li & 7) << 3;
  const int prow = li * 64;
  const u16* mrow = mp + bh * (N_ / 16) * N_ + qw + li;

  stageK(0, 0); stageV(0, 0);
  __syncthreads();
  int cur = 0;

  for (int kj0 = 0; kj0 < N_; kj0 += 64) {
    if (kj0 + 64 < N_) { stageK(cur ^ 1, kj0 + 64); stageV(cur ^ 1, kj0 + 64); }
    unsigned mword[4];
#pragma unroll
    for (int t = 0; t < 4; ++t) mword[t] = mrow[(size_t)((kj0 >> 4) + t) * N_];

    f32x4 s[4];
    __builtin_amdgcn_s_setprio(1);
#pragma unroll
    for (int t = 0; t < 4; ++t) {
      const int row = t * 16 + li;
      const int rs = row & 7;
      const bf16x8 ka0 = ld_frag(&Kt[cur][row * 64 + ((grp ^ rs) * 8)]);
      const bf16x8 ka1 = ld_frag(&Kt[cur][row * 64 + (((grp + 4) ^ rs) * 8)]);
      f32x4 z = {0.f, 0.f, 0.f, 0.f};
      z = __builtin_amdgcn_mfma_f32_16x16x32_bf16(ka0, bq0, z, 0, 0, 0);
      z = __builtin_amdgcn_mfma_f32_16x16x32_bf16(ka1, bq1, z, 0, 0, 0);
      s[t] = z;
    }
    __builtin_amdgcn_s_setprio(0);

    float sv[16];
    float rmax = -INFINITY;
#pragma unroll
    for (int t = 0; t < 4; ++t) {
      const unsigned mb = (mword[t] >> (grp * 4)) & 0xFu;
#pragma unroll
      for (int j = 0; j < 4; ++j) {
        const float x = ((mb >> j) & 1u) ? -INFINITY : s[t][j];
        sv[t * 4 + j] = x;
        rmax = fmaxf(rmax, x);
      }
    }
    rmax = fmaxf(rmax, __shfl_xor(rmax, 16));
    rmax = fmaxf(rmax, __shfl_xor(rmax, 32));
    if (!__all(rmax <= m + 8.f)) {
      const float mnew = fmaxf(m, rmax);
      const float scal = (m == -INFINITY) ? 0.f : __expf(m - mnew);
      lsum *= scal;
#pragma unroll
      for (int t2 = 0; t2 < 4; ++t2) accO[t2] *= scal;
      m = mnew;
    }
    const float msafe = (m == -INFINITY) ? 0.f : m;
    float psum = 0.f;
    float pv[16];
#pragma unroll
    for (int i = 0; i < 16; ++i) {
      const float e = __expf(sv[i] - msafe);
      pv[i] = e;
      psum += e;
    }
    psum += __shfl_xor(psum, 16);
    psum += __shfl_xor(psum, 32);
    lsum += psum;
#pragma unroll
    for (int t = 0; t < 4; ++t) {
      us4 pk;
      pk[0] = f2bu(pv[t * 4 + 0]); pk[1] = f2bu(pv[t * 4 + 1]);
      pk[2] = f2bu(pv[t * 4 + 2]); pk[3] = f2bu(pv[t * 4 + 3]);
      *(us4*)&Pw[prow + ((t * 16 + grp * 4) ^ sw)] = pk;
    }
    __builtin_amdgcn_s_setprio(1);
#pragma unroll
    for (int kc = 0; kc < 2; ++kc) {
      const bf16x8 pb = ld_frag(&Pw[prow + ((kc * 32 + grp * 8) ^ sw)]);
#pragma unroll
      for (int t2 = 0; t2 < 4; ++t2) {
        const int row = t2 * 16 + li;
        const bf16x8 va = ld_frag(&Vt[cur][row * 64 + (((kc * 4 + grp) ^ (row & 7)) * 8)]);
        accO[t2] = __builtin_amdgcn_mfma_f32_16x16x32_bf16(va, pb, accO[t2], 0, 0, 0);
      }
    }
    __builtin_amdgcn_s_setprio(0);
    __syncthreads();
    cur ^= 1;
  }
  const float inv = (lsum > 0.f) ? 1.0f / lsum : 0.f;
  u16* op = outp + ((size_t)b * N_ + qw + li) * D_ + h * DH_;
#pragma unroll
  for (int t2 = 0; t2 < 4; ++t2) {
    us4 ov;
    ov[0] = f2bu(accO[t2][0] * inv); ov[1] = f2bu(accO[t2][1] * inv);
    ov[2] = f2bu(accO[t2][2] * inv); ov[3] = f2bu(accO[t2][3] * inv);
    *(us4*)&op[t2 * 16 + grp * 4] = ov;
  }
}

// ---------------------------------------------------------------------------
// Row LayerNorm over bf16 input (768 = 256*3).
template<int OUTF32>
__global__ __launch_bounds__(256)
void ln_kernel(const u16* __restrict__ x, const float* __restrict__ g,
               const float* __restrict__ be, u16* __restrict__ ybf,
               float* __restrict__ yf) {
  const int row = blockIdx.x;
  const int t = threadIdx.x;
  const u16* xr = x + (size_t)row * D_;
  const float v0 = b2f(xr[t]), v1 = b2f(xr[t + 256]), v2 = b2f(xr[t + 512]);
  float s = v0 + v1 + v2;
  float s2 = v0 * v0 + v1 * v1 + v2 * v2;
#pragma unroll
  for (int d = 1; d < 64; d <<= 1) { s += __shfl_xor(s, d); s2 += __shfl_xor(s2, d); }
  __shared__ float red[8];
  const int w = t >> 6;
  if ((t & 63) == 0) { red[w] = s; red[4 + w] = s2; }
  __syncthreads();
  s = red[0] + red[1] + red[2] + red[3];
  s2 = red[4] + red[5] + red[6] + red[7];
  const float mu = s * (1.0f / D_);
  const float var = fmaxf(s2 * (1.0f / D_) - mu * mu, 0.0f);
  const float rstd = rsqrtf(var + 1e-5f);
#pragma unroll
  for (int c = 0; c < 3; ++c) {
    const int idx = t + c * 256;
    const float vv = (c == 0) ? v0 : (c == 1) ? v1 : v2;
    const float o = (vv - mu) * rstd * g[idx] + be[idx];
    if constexpr (OUTF32) yf[(size_t)row * D_ + idx] = o;
    else ybf[(size_t)row * D_ + idx] = f2bu(o);
  }
}

// ---------------------------------------------------------------------------
extern "C" void kernel_launch(void* const* d_in, const int* in_sizes, int n_in,
                              void* d_out, int out_size, void* d_ws, size_t ws_size,
                              hipStream_t stream) {
  (void)in_sizes; (void)n_in; (void)out_size; (void)ws_size;
  const float* nodes = (const float*)d_in[0];
  const float* rel   = (const float*)d_in[1];
  const int*   nmask = (const int*)d_in[2];
  const float* Wq = (const float*)d_in[3];
  const float* bq = (const float*)d_in[4];
  const float* Wk = (const float*)d_in[5];
  const float* bk = (const float*)d_in[6];
  const float* Wv = (const float*)d_in[7];
  const float* bv = (const float*)d_in[8];
  const float* Wo = (const float*)d_in[9];
  const float* bo = (const float*)d_in[10];
  const float* ln1g = (const float*)d_in[11];
  const float* ln1b = (const float*)d_in[12];
  const float* W1 = (const float*)d_in[13];
  const float* b1 = (const float*)d_in[14];
  const float* W2 = (const float*)d_in[15];
  const float* b2 = (const float*)d_in[16];
  const float* ln2g = (const float*)d_in[17];
  const float* ln2b = (const float*)d_in[18];
  float* out = (float*)d_out;

  char* ws = (char*)d_ws;
  u16* Wqkv_bf = (u16*)(ws + 0);         // [Wq;Wk;Wv] 2304x768
  u16* Wo_bf  = (u16*)(ws + 3538944);
  u16* W1_bf  = (u16*)(ws + 4718592);
  u16* W2_bf  = (u16*)(ws + 7077888);
  u16* Xbf    = (u16*)(ws + 9437184);    // nodes bf16; later reused as attn-out
  u16* qb     = (u16*)(ws + 22020096);   // (b,h,i,dh)
  u16* kb     = (u16*)(ws + 34603008);
  u16* vTb    = (u16*)(ws + 47185920);   // (b,h,dh,i)
  u16* mwb    = (u16*)(ws + 59768832);   // packed mask words; later reused as f1
  u16* prehb  = (u16*)(ws + 22020096);   // bf16, overlays dead qb
  u16* hbf    = (u16*)(ws + 47185920);   // overlays dead vT
  u16* f1b    = (u16*)(ws + 59768832);   // overlays dead mask
  u16* preob  = (u16*)(ws + 84934656);   // bf16
  u16* attno  = Xbf;

  const dim3 blk(256);
  // mask first: its 335 MB sweep runs before bf16 operands are produced
  build_mask_packed<<<dim3(4, 64, 8), blk, 0, stream>>>(rel, nmask, mwb);
  // single fused convert launch
  CvtArgs ca;
  ca.src[0] = Wq; ca.src[1] = Wk; ca.src[2] = Wv; ca.src[3] = Wo;
  ca.src[4] = W1; ca.src[5] = W2; ca.src[6] = nodes;
  ca.dst[0] = Wqkv_bf; ca.dst[1] = Wqkv_bf + 768 * 768; ca.dst[2] = Wqkv_bf + 2 * 768 * 768;
  ca.dst[3] = Wo_bf; ca.dst[4] = W1_bf; ca.dst[5] = W2_bf; ca.dst[6] = Xbf;
  ca.n4[0] = ca.n4[1] = ca.n4[2] = ca.n4[3] = 147456;
  ca.n4[4] = ca.n4[5] = 294912; ca.n4[6] = 1572864;
  ca.start[0] = 0; ca.start[1] = 576; ca.start[2] = 1152; ca.start[3] = 1728;
  ca.start[4] = 2304; ca.start[5] = 3456; ca.start[6] = 4608; ca.start[7] = 10752;
  cvt_all<<<10752, blk, 0, stream>>>(ca);
  // fused Q,K,V projection: 256^2 counted-vmcnt template, N=2304
  gemm256<0><<<288, dim3(512), 0, stream>>>(Xbf, Wqkv_bf, bq, bk, bv,
                                            qb, kb, vTb, 2304);
  // attention (1D XCD-chunked grid, 512 threads)
  attn<<<768, dim3(512), 0, stream>>>(qb, kb, vTb, mwb, attno);
  // out-proj + fp32 residual(nodes) -> bf16 pre_h
  gemm_bt<2><<<dim3(6, 64), blk, 0, stream>>>(attno, Wo_bf, bo, nodes, nullptr,
                                              prehb, 8192, 768, 768);
  // LN1 -> bf16 h
  ln_kernel<0><<<8192, blk, 0, stream>>>(prehb, ln1g, ln1b, hbf, nullptr);
  // FFN1 + gelu -> bf16 (256^2 template, N=1536)
  gemm256<1><<<192, dim3(512), 0, stream>>>(hbf, W1_bf, b1, nullptr, nullptr,
                                            f1b, nullptr, nullptr, 1536);
  // FFN2 + bf16 residual(h) -> bf16 pre_out
  gemm_bt<4><<<dim3(6, 64), blk, 0, stream>>>(f1b, W2_bf, b2, nullptr, hbf,
                                              preob, 8192, 768, 1536);
  // LN2 -> fp32 output
  ln_kernel<1><<<8192, blk, 0, stream>>>(preob, ln2g, ln2b, nullptr, out);
}

// Round 7
// 310.929 us; speedup vs baseline: 1.2245x; 1.2245x over previous
//
#include <hip/hip_runtime.h>
#include <stdint.h>
#include <math.h>

typedef unsigned short u16;
typedef __bf16 bf16x8 __attribute__((ext_vector_type(8)));
typedef unsigned short u16x8 __attribute__((ext_vector_type(8)));
typedef unsigned short us4 __attribute__((ext_vector_type(4)));
typedef float f32x4 __attribute__((ext_vector_type(4)));

#define DEVI __device__ __forceinline__

constexpr int B_ = 8, N_ = 1024, D_ = 768, H_ = 12, DH_ = 64, DF_ = 1536;

// float -> bf16 bits, round-to-nearest-even (finite inputs only)
DEVI u16 f2bu(float f) {
  unsigned x = __builtin_bit_cast(unsigned, f);
  x += 0x7FFFu + ((x >> 16) & 1u);
  return (u16)(x >> 16);
}
DEVI float b2f(u16 u) { return __builtin_bit_cast(float, (unsigned)u << 16); }

DEVI bf16x8 ld_frag(const u16* p) {
  return __builtin_bit_cast(bf16x8, *(const u16x8*)p);
}

DEVI void gload_lds16(const u16* g, u16* l) {
  __builtin_amdgcn_global_load_lds(
      (const __attribute__((address_space(1))) void*)g,
      (__attribute__((address_space(3))) void*)l, 16, 0, 0);
}

// ---------------------------------------------------------------------------
// All fp32 -> bf16 converts in ONE launch (7 jobs).
struct CvtArgs {
  const float* src[7];
  u16* dst[7];
  int n4[7];
  int start[8];  // cumulative block starts
};
__global__ __launch_bounds__(256)
void cvt_all(CvtArgs a) {
  const int gb = blockIdx.x;
  int j = 0;
  while (gb >= a.start[j + 1]) ++j;
  const int i = (gb - a.start[j]) * 256 + threadIdx.x;
  if (i >= a.n4[j]) return;
  float4 v = ((const float4*)a.src[j])[i];
  ushort4 o;
  o.x = f2bu(v.x); o.y = f2bu(v.y); o.z = f2bu(v.z); o.w = f2bu(v.w);
  ((ushort4*)a.dst[j])[i] = o;
}

// ---------------------------------------------------------------------------
// Compress relation_mask (B,N,N,R fp32) + node_mask into bit-packed,
// head-separated, k-transposed words:
//   mp[((b*H + h)*(N/16) + kt)*N + q], bit j = "head h masked at k = kt*16+j".
__global__ __launch_bounds__(256)
void build_mask_packed(const float* __restrict__ rel, const int* __restrict__ nm,
                       u16* __restrict__ mp) {
  const int b = blockIdx.z, q0 = blockIdx.y * 16, k0 = blockIdx.x * 256;
  const int t = threadIdx.x;
  __shared__ u16 w12[16][256];
  const int key_ok = nm[(b << 10) + k0 + t];
  const float th = 1e-4f;
#pragma unroll 1
  for (int it = 0; it < 16; ++it) {
    unsigned bits;
    if (!key_ok) {
      bits = 0xFFFu;
    } else {
      const size_t idx = (((size_t)(b << 10) + q0 + it) << 10) + k0 + t;
      const float2* rp = (const float2*)(rel + idx * 10);
      float2 a0 = rp[0], a1 = rp[1], a2 = rp[2], a3 = rp[3], a4 = rp[4];
      bits  = (a0.x < th ? 1u : 0u)   | (a0.y < th ? 2u : 0u)
            | (a1.x < th ? 4u : 0u)   | (a1.y < th ? 8u : 0u)
            | (a2.x < th ? 16u : 0u)  | (a2.y < th ? 32u : 0u)
            | (a3.x < th ? 64u : 0u)  | (a3.y < th ? 128u : 0u)
            | (a4.x < th ? 256u : 0u) | (a4.y < th ? 512u : 0u);
    }
    w12[it][t ^ ((it & 7) << 1)] = (u16)bits;
  }
  __syncthreads();
  const int ql = t & 15, kt = t >> 4;
  unsigned wv[16];
#pragma unroll
  for (int j2 = 0; j2 < 8; ++j2) {
    const int e = (kt * 16 + j2 * 2) ^ ((ql & 7) << 1);
    wv[j2 * 2] = w12[ql][e];
    wv[j2 * 2 + 1] = w12[ql][e + 1];
  }
#pragma unroll
  for (int h = 0; h < 12; ++h) {
    unsigned word = 0;
#pragma unroll
    for (int j = 0; j < 16; ++j) word |= ((wv[j] >> h) & 1u) << j;
    mp[(((size_t)(b * H_ + h)) * (N_ / 16) + (k0 >> 4) + kt) * N_ + q0 + ql] = (u16)word;
  }
}

// ---------------------------------------------------------------------------
// C = A(MxK) @ B(NxK)^T (+epilogue). 128x128 tile, BK=32, 4 waves,
// TRIPLE-buffered global_load_lds staging with counted vmcnt (never drains
// to 0 in steady state): each thread issues exactly 4 loads per K-tile, so
// "s_waitcnt vmcnt(4)" at tile end == "tile t+1 landed, t+2 in flight".
// lgkmcnt(0) folded in so all frag ds_reads complete before the barrier
// (closes the rule-#18 MFMA-sink race on buffer reuse).
// EPI: 0 = QK split write (Q pre-scaled by 1/8) to (b,h,i,dh);
//      1 = vT write (b,h,dh,i);
//      2 = +bias +fp32 resid -> bf16;   3 = +bias, gelu -> bf16;
//      4 = +bias +bf16 resid -> bf16
template<int EPI>
__global__ __launch_bounds__(256, 3)
void gemm_bt(const u16* __restrict__ A, const u16* __restrict__ Bm,
             const float* __restrict__ bias0, const float* __restrict__ bias1,
             const float* __restrict__ residf, const u16* __restrict__ residb,
             u16* __restrict__ out0, u16* __restrict__ out1,
             int M, int N, int K) {
  __shared__ u16 As[3][128 * 32];
  __shared__ u16 Bs[3][128 * 32];
  const int t = threadIdx.x;
  const int w = t >> 6, l = t & 63;
  const int li = l & 15, grp = l >> 4;
  // bijective XCD swizzle (all grids are multiples of 8)
  const int nwg = gridDim.x * gridDim.y;
  int id = blockIdx.y * gridDim.x + blockIdx.x;
  id = (id & 7) * (nwg >> 3) + (id >> 3);
  const int by = id / gridDim.x;
  const int bx = id - by * gridDim.x;
  const int n0 = bx * 128, m0 = by * 128;
  const int wr = w >> 1, wc = w & 1;

  f32x4 acc[4][4] = {};

  const int arow = w * 16 + (l >> 2);
  const int acol = (l & 3) * 8;
  const u16* Ag = A + (size_t)(m0 + arow) * K + acol;
  const u16* Bg = Bm + (size_t)(n0 + arow) * K + acol;
  const int NT = K >> 5;

  auto stage = [&](int buf, int kt) {
    u16* Asw = &As[buf][(w * 16) * 32];
    u16* Bsw = &Bs[buf][(w * 16) * 32];
    const int k0 = kt * 32;
    gload_lds16(Ag + k0, Asw);
    gload_lds16(Ag + (size_t)64 * K + k0, Asw + 64 * 32);
    gload_lds16(Bg + k0, Bsw);
    gload_lds16(Bg + (size_t)64 * K + k0, Bsw + 64 * 32);
  };

  // prologue: tiles 0,1 in flight; wait tile 0 (4 newest = tile 1 stay out)
  stage(0, 0); stage(1, 1);
  asm volatile("s_waitcnt vmcnt(4)\n\ts_barrier" ::: "memory");

  for (int kt = 0; kt < NT; ++kt) {
    const int bt = kt % 3;
    const bool pre = (kt + 2 < NT);
    if (pre) stage((kt + 2) % 3, kt + 2);   // prefetch 2 tiles ahead
    bf16x8 af[4], bfr[4];
#pragma unroll
    for (int m = 0; m < 4; ++m)
      af[m] = ld_frag(&As[bt][(wr * 64 + m * 16 + li) * 32 + grp * 8]);
#pragma unroll
    for (int n = 0; n < 4; ++n)
      bfr[n] = ld_frag(&Bs[bt][(wc * 64 + n * 16 + li) * 32 + grp * 8]);
    __builtin_amdgcn_s_setprio(1);
#pragma unroll
    for (int m = 0; m < 4; ++m)
#pragma unroll
      for (int n = 0; n < 4; ++n)
        acc[m][n] = __builtin_amdgcn_mfma_f32_16x16x32_bf16(af[m], bfr[n], acc[m][n], 0, 0, 0);
    __builtin_amdgcn_s_setprio(0);
    if (pre) asm volatile("s_waitcnt vmcnt(4) lgkmcnt(0)\n\ts_barrier" ::: "memory");
    else     asm volatile("s_waitcnt vmcnt(0) lgkmcnt(0)\n\ts_barrier" ::: "memory");
  }

#pragma unroll
  for (int m = 0; m < 4; ++m) {
#pragma unroll
    for (int n = 0; n < 4; ++n) {
#pragma unroll
      for (int j = 0; j < 4; ++j) {
        const int row = m0 + wr * 64 + m * 16 + grp * 4 + j;
        const int col = n0 + wc * 64 + n * 16 + li;
        float v = acc[m][n][j];
        if constexpr (EPI == 0) {
          v += (col < D_) ? bias0[col] : bias1[col - D_];
          if (col < D_) v *= 0.125f;   // fold 1/sqrt(DH) into Q
          const int b = row >> 10, i = row & (N_ - 1);
          int c2 = (col < D_) ? col : col - D_;
          u16* dst = (col < D_) ? out0 : out1;
          dst[(((size_t)(b * H_ + (c2 >> 6))) * N_ + i) * DH_ + (c2 & 63)] = f2bu(v);
        } else if constexpr (EPI == 1) {
          v += bias0[row];
          const int b = col >> 10, i = col & (N_ - 1);
          out0[(((size_t)(b * H_ + (row >> 6))) * DH_ + (row & 63)) * N_ + i] = f2bu(v);
        } else if constexpr (EPI == 2) {
          v += bias0[col] + residf[(size_t)row * N + col];
          out0[(size_t)row * N + col] = f2bu(v);
        } else if constexpr (EPI == 3) {  // gelu(exact) -> bf16
          v += bias0[col];
          float gel = 0.5f * v * (1.0f + erff(v * 0.70710678118654752440f));
          out0[(size_t)row * N + col] = f2bu(gel);
        } else {  // EPI == 4: +bias + bf16 resid -> bf16
          v += bias0[col] + b2f(residb[(size_t)row * N + col]);
          out0[(size_t)row * N + col] = f2bu(v);
        }
      }
    }
  }
}

// ---------------------------------------------------------------------------
// Flash attention, swapped-operand + LDS-staged K/V, lean softmax (round-5).
__global__ __launch_bounds__(512, 4)
void attn(const u16* __restrict__ q, const u16* __restrict__ k, const u16* __restrict__ vT,
          const u16* __restrict__ mp, u16* __restrict__ outp) {
  const int nwg = gridDim.x;
  const int p = blockIdx.x;
  const int lid = (p & 7) * (nwg >> 3) + (p >> 3);
  const int bh_i = lid >> 3;       // (b*H + h)
  const int qblk = lid & 7;
  const int b = bh_i / H_, h = bh_i - (bh_i / H_) * H_;
  const int w = threadIdx.x >> 6, l = threadIdx.x & 63;
  const int li = l & 15, grp = l >> 4;
  const int qw = qblk * 128 + w * 16;
  const size_t bh = (size_t)bh_i;

  __shared__ u16 Kt[2][64 * 64];   // [k-local][d], swizzled
  __shared__ u16 Vt[2][64 * 64];   // [d][k-local], swizzled
  __shared__ u16 P[8][16 * 64];    // per-wave [q=li][k-local], swizzled

  const u16* kbase = k + bh * N_ * DH_;
  const u16* vbase = vT + bh * DH_ * N_;

  const int srow_off = l >> 3;          // 0..7
  const int sg = l & 7;                 // dest granule
  const int r0 = w * 8;
  auto stageK = [&](int buf, int kj0) {
    const int row = r0 + srow_off;
    const int gp = sg ^ (row & 7);
    gload_lds16(kbase + (size_t)(kj0 + row) * DH_ + gp * 8, &Kt[buf][r0 * 64]);
  };
  auto stageV = [&](int buf, int kj0) {
    const int row = r0 + srow_off;
    const int gp = sg ^ (row & 7);
    gload_lds16(vbase + (size_t)row * N_ + kj0 + gp * 8, &Vt[buf][r0 * 64]);
  };

  const u16* qp = q + (bh * N_ + qw) * DH_;
  const bf16x8 bq0 = ld_frag(qp + li * DH_ + grp * 8);
  const bf16x8 bq1 = ld_frag(qp + li * DH_ + 32 + grp * 8);

  f32x4 accO[4] = {};            // O^T: d = t2*16+grp*4+j, q = li
  float m = -INFINITY, lsum = 0.f;

  u16* Pw = &P[w][0];
  const int sw = (li & 7) << 3;
  const int prow = li * 64;
  const u16* mrow = mp + bh * (N_ / 16) * N_ + qw + li;

  stageK(0, 0); stageV(0, 0);
  __syncthreads();
  int cur = 0;

  for (int kj0 = 0; kj0 < N_; kj0 += 64) {
    if (kj0 + 64 < N_) { stageK(cur ^ 1, kj0 + 64); stageV(cur ^ 1, kj0 + 64); }
    unsigned mword[4];
#pragma unroll
    for (int t = 0; t < 4; ++t) mword[t] = mrow[(size_t)((kj0 >> 4) + t) * N_];

    f32x4 s[4];
    __builtin_amdgcn_s_setprio(1);
#pragma unroll
    for (int t = 0; t < 4; ++t) {
      const int row = t * 16 + li;
      const int rs = row & 7;
      const bf16x8 ka0 = ld_frag(&Kt[cur][row * 64 + ((grp ^ rs) * 8)]);
      const bf16x8 ka1 = ld_frag(&Kt[cur][row * 64 + (((grp + 4) ^ rs) * 8)]);
      f32x4 z = {0.f, 0.f, 0.f, 0.f};
      z = __builtin_amdgcn_mfma_f32_16x16x32_bf16(ka0, bq0, z, 0, 0, 0);
      z = __builtin_amdgcn_mfma_f32_16x16x32_bf16(ka1, bq1, z, 0, 0, 0);
      s[t] = z;
    }
    __builtin_amdgcn_s_setprio(0);

    float sv[16];
    float rmax = -INFINITY;
#pragma unroll
    for (int t = 0; t < 4; ++t) {
      const unsigned mb = (mword[t] >> (grp * 4)) & 0xFu;
#pragma unroll
      for (int j = 0; j < 4; ++j) {
        const float x = ((mb >> j) & 1u) ? -INFINITY : s[t][j];
        sv[t * 4 + j] = x;
        rmax = fmaxf(rmax, x);
      }
    }
    rmax = fmaxf(rmax, __shfl_xor(rmax, 16));
    rmax = fmaxf(rmax, __shfl_xor(rmax, 32));
    if (!__all(rmax <= m + 8.f)) {
      const float mnew = fmaxf(m, rmax);
      const float scal = (m == -INFINITY) ? 0.f : __expf(m - mnew);
      lsum *= scal;
#pragma unroll
      for (int t2 = 0; t2 < 4; ++t2) accO[t2] *= scal;
      m = mnew;
    }
    const float msafe = (m == -INFINITY) ? 0.f : m;
    float psum = 0.f;
    float pv[16];
#pragma unroll
    for (int i = 0; i < 16; ++i) {
      const float e = __expf(sv[i] - msafe);
      pv[i] = e;
      psum += e;
    }
    psum += __shfl_xor(psum, 16);
    psum += __shfl_xor(psum, 32);
    lsum += psum;
#pragma unroll
    for (int t = 0; t < 4; ++t) {
      us4 pk;
      pk[0] = f2bu(pv[t * 4 + 0]); pk[1] = f2bu(pv[t * 4 + 1]);
      pk[2] = f2bu(pv[t * 4 + 2]); pk[3] = f2bu(pv[t * 4 + 3]);
      *(us4*)&Pw[prow + ((t * 16 + grp * 4) ^ sw)] = pk;
    }
    __builtin_amdgcn_s_setprio(1);
#pragma unroll
    for (int kc = 0; kc < 2; ++kc) {
      const bf16x8 pb = ld_frag(&Pw[prow + ((kc * 32 + grp * 8) ^ sw)]);
#pragma unroll
      for (int t2 = 0; t2 < 4; ++t2) {
        const int row = t2 * 16 + li;
        const bf16x8 va = ld_frag(&Vt[cur][row * 64 + (((kc * 4 + grp) ^ (row & 7)) * 8)]);
        accO[t2] = __builtin_amdgcn_mfma_f32_16x16x32_bf16(va, pb, accO[t2], 0, 0, 0);
      }
    }
    __builtin_amdgcn_s_setprio(0);
    __syncthreads();
    cur ^= 1;
  }
  const float inv = (lsum > 0.f) ? 1.0f / lsum : 0.f;  // all-masked row -> 0
  u16* op = outp + ((size_t)b * N_ + qw + li) * D_ + h * DH_;
#pragma unroll
  for (int t2 = 0; t2 < 4; ++t2) {
    us4 ov;
    ov[0] = f2bu(accO[t2][0] * inv); ov[1] = f2bu(accO[t2][1] * inv);
    ov[2] = f2bu(accO[t2][2] * inv); ov[3] = f2bu(accO[t2][3] * inv);
    *(us4*)&op[t2 * 16 + grp * 4] = ov;
  }
}

// ---------------------------------------------------------------------------
// Row LayerNorm over bf16 input (768 = 256*3).
// OUTF32=0: write bf16 ybf; OUTF32=1: write fp32 yf.
template<int OUTF32>
__global__ __launch_bounds__(256)
void ln_kernel(const u16* __restrict__ x, const float* __restrict__ g,
               const float* __restrict__ be, u16* __restrict__ ybf,
               float* __restrict__ yf) {
  const int row = blockIdx.x;
  const int t = threadIdx.x;
  const u16* xr = x + (size_t)row * D_;
  const float v0 = b2f(xr[t]), v1 = b2f(xr[t + 256]), v2 = b2f(xr[t + 512]);
  float s = v0 + v1 + v2;
  float s2 = v0 * v0 + v1 * v1 + v2 * v2;
#pragma unroll
  for (int d = 1; d < 64; d <<= 1) { s += __shfl_xor(s, d); s2 += __shfl_xor(s2, d); }
  __shared__ float red[8];
  const int w = t >> 6;
  if ((t & 63) == 0) { red[w] = s; red[4 + w] = s2; }
  __syncthreads();
  s = red[0] + red[1] + red[2] + red[3];
  s2 = red[4] + red[5] + red[6] + red[7];
  const float mu = s * (1.0f / D_);
  const float var = fmaxf(s2 * (1.0f / D_) - mu * mu, 0.0f);
  const float rstd = rsqrtf(var + 1e-5f);
#pragma unroll
  for (int c = 0; c < 3; ++c) {
    const int idx = t + c * 256;
    const float vv = (c == 0) ? v0 : (c == 1) ? v1 : v2;
    const float o = (vv - mu) * rstd * g[idx] + be[idx];
    if constexpr (OUTF32) yf[(size_t)row * D_ + idx] = o;
    else ybf[(size_t)row * D_ + idx] = f2bu(o);
  }
}

// ---------------------------------------------------------------------------
extern "C" void kernel_launch(void* const* d_in, const int* in_sizes, int n_in,
                              void* d_out, int out_size, void* d_ws, size_t ws_size,
                              hipStream_t stream) {
  (void)in_sizes; (void)n_in; (void)out_size; (void)ws_size;
  const float* nodes = (const float*)d_in[0];
  const float* rel   = (const float*)d_in[1];
  const int*   nmask = (const int*)d_in[2];
  const float* Wq = (const float*)d_in[3];
  const float* bq = (const float*)d_in[4];
  const float* Wk = (const float*)d_in[5];
  const float* bk = (const float*)d_in[6];
  const float* Wv = (const float*)d_in[7];
  const float* bv = (const float*)d_in[8];
  const float* Wo = (const float*)d_in[9];
  const float* bo = (const float*)d_in[10];
  const float* ln1g = (const float*)d_in[11];
  const float* ln1b = (const float*)d_in[12];
  const float* W1 = (const float*)d_in[13];
  const float* b1 = (const float*)d_in[14];
  const float* W2 = (const float*)d_in[15];
  const float* b2 = (const float*)d_in[16];
  const float* ln2g = (const float*)d_in[17];
  const float* ln2b = (const float*)d_in[18];
  float* out = (float*)d_out;

  char* ws = (char*)d_ws;
  u16* Wqk_bf = (u16*)(ws + 0);          // [Wq;Wk] 1536x768
  u16* Wv_bf  = (u16*)(ws + 2359296);
  u16* Wo_bf  = (u16*)(ws + 3538944);
  u16* W1_bf  = (u16*)(ws + 4718592);
  u16* W2_bf  = (u16*)(ws + 7077888);
  u16* Xbf    = (u16*)(ws + 9437184);    // nodes bf16; later reused as attn-out
  u16* qb     = (u16*)(ws + 22020096);   // (b,h,i,dh)
  u16* kb     = (u16*)(ws + 34603008);
  u16* vTb    = (u16*)(ws + 47185920);   // (b,h,dh,i)
  u16* mwb    = (u16*)(ws + 59768832);   // packed mask words; later reused as f1
  u16* prehb  = (u16*)(ws + 22020096);   // bf16, overlays dead qb
  u16* hbf    = (u16*)(ws + 47185920);   // overlays dead vT
  u16* f1b    = (u16*)(ws + 59768832);   // overlays dead mask
  u16* preob  = (u16*)(ws + 84934656);   // bf16
  u16* attno  = Xbf;

  const dim3 blk(256);
  // mask first: its 335 MB sweep runs before bf16 operands are produced
  build_mask_packed<<<dim3(4, 64, 8), blk, 0, stream>>>(rel, nmask, mwb);
  // single fused convert launch
  CvtArgs ca;
  ca.src[0] = Wq; ca.src[1] = Wk; ca.src[2] = Wv; ca.src[3] = Wo;
  ca.src[4] = W1; ca.src[5] = W2; ca.src[6] = nodes;
  ca.dst[0] = Wqk_bf; ca.dst[1] = Wqk_bf + 768 * 768; ca.dst[2] = Wv_bf;
  ca.dst[3] = Wo_bf; ca.dst[4] = W1_bf; ca.dst[5] = W2_bf; ca.dst[6] = Xbf;
  ca.n4[0] = ca.n4[1] = ca.n4[2] = ca.n4[3] = 147456;
  ca.n4[4] = ca.n4[5] = 294912; ca.n4[6] = 1572864;
  ca.start[0] = 0; ca.start[1] = 576; ca.start[2] = 1152; ca.start[3] = 1728;
  ca.start[4] = 2304; ca.start[5] = 3456; ca.start[6] = 4608; ca.start[7] = 10752;
  cvt_all<<<10752, blk, 0, stream>>>(ca);
  // fused Q,K projection (N=1536), Q pre-scaled by 1/8
  gemm_bt<0><<<dim3(12, 64), blk, 0, stream>>>(Xbf, Wqk_bf, bq, bk, nullptr, nullptr,
                                               qb, kb, 8192, 1536, 768);
  // V projection, transposed output: C = Wv @ X^T  (M=768, N=8192)
  gemm_bt<1><<<dim3(64, 6), blk, 0, stream>>>(Wv_bf, Xbf, bv, nullptr, nullptr, nullptr,
                                              vTb, nullptr, 768, 8192, 768);
  // attention (1D XCD-chunked grid, 512 threads)
  attn<<<768, dim3(512), 0, stream>>>(qb, kb, vTb, mwb, attno);
  // out-proj + fp32 residual(nodes) -> bf16 pre_h
  gemm_bt<2><<<dim3(6, 64), blk, 0, stream>>>(attno, Wo_bf, bo, nullptr, nodes, nullptr,
                                              prehb, nullptr, 8192, 768, 768);
  // LN1 -> bf16 h
  ln_kernel<0><<<8192, blk, 0, stream>>>(prehb, ln1g, ln1b, hbf, nullptr);
  // FFN1 + gelu -> bf16
  gemm_bt<3><<<dim3(12, 64), blk, 0, stream>>>(hbf, W1_bf, b1, nullptr, nullptr, nullptr,
                                               f1b, nullptr, 8192, 1536, 768);
  // FFN2 + bf16 residual(h) -> bf16 pre_out
  gemm_bt<4><<<dim3(6, 64), blk, 0, stream>>>(f1b, W2_bf, b2, nullptr, nullptr, hbf,
                                              preob, nullptr, 8192, 768, 1536);
  // LN2 -> fp32 output
  ln_kernel<1><<<8192, blk, 0, stream>>>(preob, ln2g, ln2b, nullptr, out);
}

// Round 8
// 298.498 us; speedup vs baseline: 1.2755x; 1.0416x over previous
//
#include <hip/hip_runtime.h>
#include <stdint.h>
#include <math.h>

typedef unsigned short u16;
typedef __bf16 bf16x8 __attribute__((ext_vector_type(8)));
typedef __bf16 bf16x2 __attribute__((ext_vector_type(2)));
typedef unsigned short u16x8 __attribute__((ext_vector_type(8)));
typedef float f32x4 __attribute__((ext_vector_type(4)));

#define DEVI __device__ __forceinline__

constexpr int B_ = 8, N_ = 1024, D_ = 768, H_ = 12, DH_ = 64, DF_ = 1536;

// float -> bf16 bits, round-to-nearest-even (finite inputs only)
DEVI u16 f2bu(float f) {
  unsigned x = __builtin_bit_cast(unsigned, f);
  x += 0x7FFFu + ((x >> 16) & 1u);
  return (u16)(x >> 16);
}
DEVI float b2f(u16 u) { return __builtin_bit_cast(float, (unsigned)u << 16); }

DEVI bf16x8 ld_frag(const u16* p) {
  return __builtin_bit_cast(bf16x8, *(const u16x8*)p);
}

DEVI void gload_lds16(const u16* g, u16* l) {
  __builtin_amdgcn_global_load_lds(
      (const __attribute__((address_space(1))) void*)g,
      (__attribute__((address_space(3))) void*)l, 16, 0, 0);
}

// ---------------------------------------------------------------------------
// prep_all: ONE launch = relation-mask bit-packing (blocks 0..2047) + all
// seven fp32->bf16 converts (blocks 2048..12799).
struct CvtArgs {
  const float* src[7];
  u16* dst[7];
  int n4[7];
  int start[8];  // cumulative block starts (offset by 2048)
};
__global__ __launch_bounds__(256)
void prep_all(CvtArgs a, const float* __restrict__ rel, const int* __restrict__ nm,
              u16* __restrict__ mp) {
  const int gb0 = blockIdx.x;
  const int t = threadIdx.x;
  if (gb0 < 2048) {
    // ---- mask packing: id -> (k0, q0, b) as in dim3(4,64,8) flattening
    const int b = gb0 >> 8, q0 = ((gb0 >> 2) & 63) * 16, k0 = (gb0 & 3) * 256;
    __shared__ u16 w12[16][256];
    const int key_ok = nm[(b << 10) + k0 + t];
    const float th = 1e-4f;
#pragma unroll 1
    for (int it = 0; it < 16; ++it) {
      unsigned bits;
      if (!key_ok) {
        bits = 0xFFFu;
      } else {
        const size_t idx = (((size_t)(b << 10) + q0 + it) << 10) + k0 + t;
        const float2* rp = (const float2*)(rel + idx * 10);
        float2 a0 = rp[0], a1 = rp[1], a2 = rp[2], a3 = rp[3], a4 = rp[4];
        bits  = (a0.x < th ? 1u : 0u)   | (a0.y < th ? 2u : 0u)
              | (a1.x < th ? 4u : 0u)   | (a1.y < th ? 8u : 0u)
              | (a2.x < th ? 16u : 0u)  | (a2.y < th ? 32u : 0u)
              | (a3.x < th ? 64u : 0u)  | (a3.y < th ? 128u : 0u)
              | (a4.x < th ? 256u : 0u) | (a4.y < th ? 512u : 0u);
      }
      w12[it][t ^ ((it & 7) << 1)] = (u16)bits;
    }
    __syncthreads();
    const int ql = t & 15, kt = t >> 4;
    unsigned wv[16];
#pragma unroll
    for (int j2 = 0; j2 < 8; ++j2) {
      const int e = (kt * 16 + j2 * 2) ^ ((ql & 7) << 1);
      wv[j2 * 2] = w12[ql][e];
      wv[j2 * 2 + 1] = w12[ql][e + 1];
    }
#pragma unroll
    for (int h = 0; h < 12; ++h) {
      unsigned word = 0;
#pragma unroll
      for (int j = 0; j < 16; ++j) word |= ((wv[j] >> h) & 1u) << j;
      mp[(((size_t)(b * H_ + h)) * (N_ / 16) + (k0 >> 4) + kt) * N_ + q0 + ql] = (u16)word;
    }
  } else {
    // ---- converts
    int j = 0;
    while (gb0 >= a.start[j + 1]) ++j;
    const int i = (gb0 - a.start[j]) * 256 + t;
    if (i >= a.n4[j]) return;
    float4 v = ((const float4*)a.src[j])[i];
    ushort4 o;
    o.x = f2bu(v.x); o.y = f2bu(v.y); o.z = f2bu(v.z); o.w = f2bu(v.w);
    ((ushort4*)a.dst[j])[i] = o;
  }
}

// ---------------------------------------------------------------------------
// 128x128-tile GEMM body, BK=32, 4 waves, triple-buffered counted-vmcnt
// staging (R7-verified). EPI: 0 = QK split write (Q pre-scaled 1/8);
// 1 = vT write (b,h,dh,i); 2 = +bias +fp32 resid -> bf16;
// 3 = +bias gelu -> bf16;  4 = +bias +bf16 resid -> bf16
template<int EPI>
DEVI void gemm_body(const u16* __restrict__ A, const u16* __restrict__ Bm,
                    const float* __restrict__ bias0, const float* __restrict__ bias1,
                    const float* __restrict__ residf, const u16* __restrict__ residb,
                    u16* __restrict__ out0, u16* __restrict__ out1,
                    int N, int K, int bx, int by,
                    u16 (&As)[3][128 * 32], u16 (&Bs)[3][128 * 32]) {
  const int t = threadIdx.x;
  const int w = t >> 6, l = t & 63;
  const int li = l & 15, grp = l >> 4;
  const int n0 = bx * 128, m0 = by * 128;
  const int wr = w >> 1, wc = w & 1;

  f32x4 acc[4][4] = {};

  const int arow = w * 16 + (l >> 2);
  const int acol = (l & 3) * 8;
  const u16* Ag = A + (size_t)(m0 + arow) * K + acol;
  const u16* Bg = Bm + (size_t)(n0 + arow) * K + acol;
  const int NT = K >> 5;

  auto stage = [&](int buf, int kt) {
    u16* Asw = &As[buf][(w * 16) * 32];
    u16* Bsw = &Bs[buf][(w * 16) * 32];
    const int k0 = kt * 32;
    gload_lds16(Ag + k0, Asw);
    gload_lds16(Ag + (size_t)64 * K + k0, Asw + 64 * 32);
    gload_lds16(Bg + k0, Bsw);
    gload_lds16(Bg + (size_t)64 * K + k0, Bsw + 64 * 32);
  };

  stage(0, 0); stage(1, 1);
  asm volatile("s_waitcnt vmcnt(4)\n\ts_barrier" ::: "memory");

  for (int kt = 0; kt < NT; ++kt) {
    const int bt = kt % 3;
    const bool pre = (kt + 2 < NT);
    if (pre) stage((kt + 2) % 3, kt + 2);
    bf16x8 af[4], bfr[4];
#pragma unroll
    for (int m = 0; m < 4; ++m)
      af[m] = ld_frag(&As[bt][(wr * 64 + m * 16 + li) * 32 + grp * 8]);
#pragma unroll
    for (int n = 0; n < 4; ++n)
      bfr[n] = ld_frag(&Bs[bt][(wc * 64 + n * 16 + li) * 32 + grp * 8]);
    __builtin_amdgcn_s_setprio(1);
#pragma unroll
    for (int m = 0; m < 4; ++m)
#pragma unroll
      for (int n = 0; n < 4; ++n)
        acc[m][n] = __builtin_amdgcn_mfma_f32_16x16x32_bf16(af[m], bfr[n], acc[m][n], 0, 0, 0);
    __builtin_amdgcn_s_setprio(0);
    if (pre) asm volatile("s_waitcnt vmcnt(4) lgkmcnt(0)\n\ts_barrier" ::: "memory");
    else     asm volatile("s_waitcnt vmcnt(0) lgkmcnt(0)\n\ts_barrier" ::: "memory");
  }

#pragma unroll
  for (int m = 0; m < 4; ++m) {
#pragma unroll
    for (int n = 0; n < 4; ++n) {
#pragma unroll
      for (int j = 0; j < 4; ++j) {
        const int row = m0 + wr * 64 + m * 16 + grp * 4 + j;
        const int col = n0 + wc * 64 + n * 16 + li;
        float v = acc[m][n][j];
        if constexpr (EPI == 0) {
          v += (col < D_) ? bias0[col] : bias1[col - D_];
          if (col < D_) v *= 0.125f;   // fold 1/sqrt(DH) into Q
          const int b = row >> 10, i = row & (N_ - 1);
          int c2 = (col < D_) ? col : col - D_;
          u16* dst = (col < D_) ? out0 : out1;
          dst[(((size_t)(b * H_ + (c2 >> 6))) * N_ + i) * DH_ + (c2 & 63)] = f2bu(v);
        } else if constexpr (EPI == 1) {
          v += bias0[row];
          const int b = col >> 10, i = col & (N_ - 1);
          out0[(((size_t)(b * H_ + (row >> 6))) * DH_ + (row & 63)) * N_ + i] = f2bu(v);
        } else if constexpr (EPI == 2) {
          v += bias0[col] + residf[(size_t)row * N + col];
          out0[(size_t)row * N + col] = f2bu(v);
        } else if constexpr (EPI == 3) {  // gelu(exact) -> bf16
          v += bias0[col];
          float gel = 0.5f * v * (1.0f + erff(v * 0.70710678118654752440f));
          out0[(size_t)row * N + col] = f2bu(gel);
        } else {  // EPI == 4
          v += bias0[col] + b2f(residb[(size_t)row * N + col]);
          out0[(size_t)row * N + col] = f2bu(v);
        }
      }
    }
  }
}

// Standalone 128^2 GEMM with XCD swizzle (EPI 2,3,4 shapes).
template<int EPI>
__global__ __launch_bounds__(256, 3)
void gemm_bt(const u16* __restrict__ A, const u16* __restrict__ Bm,
             const float* __restrict__ bias0,
             const float* __restrict__ residf, const u16* __restrict__ residb,
             u16* __restrict__ out0, int N, int K) {
  __shared__ u16 As[3][128 * 32];
  __shared__ u16 Bs[3][128 * 32];
  const int nwg = gridDim.x * gridDim.y;
  int id = blockIdx.y * gridDim.x + blockIdx.x;
  id = (id & 7) * (nwg >> 3) + (id >> 3);
  const int by = id / gridDim.x;
  const int bx = id - by * gridDim.x;
  gemm_body<EPI>(A, Bm, bias0, nullptr, residf, residb, out0, nullptr,
                 N, K, bx, by, As, Bs);
}

// Merged QK-projection (blocks 0..767) + V-projection (768..1151): the two
// are independent -> one launch co-fills the machine, removes a graph edge.
__global__ __launch_bounds__(256, 3)
void gemm_qkv(const u16* __restrict__ Xbf, const u16* __restrict__ Wqk,
              const u16* __restrict__ Wv,
              const float* __restrict__ bq, const float* __restrict__ bk,
              const float* __restrict__ bv,
              u16* __restrict__ qb, u16* __restrict__ kb, u16* __restrict__ vTb) {
  __shared__ u16 As[3][128 * 32];
  __shared__ u16 Bs[3][128 * 32];
  constexpr int nwg = 1152;
  int id = blockIdx.x;
  id = (id & 7) * (nwg >> 3) + (id >> 3);   // bijective XCD chunking
  if (id < 768) {
    const int by = id / 12, bx = id - by * 12;
    gemm_body<0>(Xbf, Wqk, bq, bk, nullptr, nullptr, qb, kb,
                 1536, 768, bx, by, As, Bs);
  } else {
    const int v = id - 768;
    const int by = v / 64, bx = v - by * 64;
    gemm_body<1>(Wv, Xbf, bv, nullptr, nullptr, nullptr, vTb, nullptr,
                 8192, 768, bx, by, As, Bs);
  }
}

// ---------------------------------------------------------------------------
// Flash attention, swapped-operand + LDS-staged K/V, lean softmax.
// R8: cvt_pk-paired bf16 conversions (P store + epilogue), max3-fusable
// reduction tree. Structure otherwise identical to round 5/7.
__global__ __launch_bounds__(512, 4)
void attn(const u16* __restrict__ q, const u16* __restrict__ k, const u16* __restrict__ vT,
          const u16* __restrict__ mp, u16* __restrict__ outp) {
  const int nwg = gridDim.x;
  const int p = blockIdx.x;
  const int lid = (p & 7) * (nwg >> 3) + (p >> 3);
  const int bh_i = lid >> 3;       // (b*H + h)
  const int qblk = lid & 7;
  const int b = bh_i / H_, h = bh_i - (bh_i / H_) * H_;
  const int w = threadIdx.x >> 6, l = threadIdx.x & 63;
  const int li = l & 15, grp = l >> 4;
  const int qw = qblk * 128 + w * 16;
  const size_t bh = (size_t)bh_i;

  __shared__ u16 Kt[2][64 * 64];   // [k-local][d], swizzled
  __shared__ u16 Vt[2][64 * 64];   // [d][k-local], swizzled
  __shared__ u16 P[8][16 * 64];    // per-wave [q=li][k-local], swizzled

  const u16* kbase = k + bh * N_ * DH_;
  const u16* vbase = vT + bh * DH_ * N_;

  const int srow_off = l >> 3;          // 0..7
  const int sg = l & 7;                 // dest granule
  const int r0 = w * 8;
  auto stageK = [&](int buf, int kj0) {
    const int row = r0 + srow_off;
    const int gp = sg ^ (row & 7);
    gload_lds16(kbase + (size_t)(kj0 + row) * DH_ + gp * 8, &Kt[buf][r0 * 64]);
  };
  auto stageV = [&](int buf, int kj0) {
    const int row = r0 + srow_off;
    const int gp = sg ^ (row & 7);
    gload_lds16(vbase + (size_t)row * N_ + kj0 + gp * 8, &Vt[buf][r0 * 64]);
  };

  const u16* qp = q + (bh * N_ + qw) * DH_;
  const bf16x8 bq0 = ld_frag(qp + li * DH_ + grp * 8);
  const bf16x8 bq1 = ld_frag(qp + li * DH_ + 32 + grp * 8);

  f32x4 accO[4] = {};            // O^T: d = t2*16+grp*4+j, q = li
  float m = -INFINITY, lsum = 0.f;

  u16* Pw = &P[w][0];
  const int sw = (li & 7) << 3;
  const int prow = li * 64;
  const u16* mrow = mp + bh * (N_ / 16) * N_ + qw + li;

  stageK(0, 0); stageV(0, 0);
  __syncthreads();
  int cur = 0;

  for (int kj0 = 0; kj0 < N_; kj0 += 64) {
    if (kj0 + 64 < N_) { stageK(cur ^ 1, kj0 + 64); stageV(cur ^ 1, kj0 + 64); }
    unsigned mword[4];
#pragma unroll
    for (int t = 0; t < 4; ++t) mword[t] = mrow[(size_t)((kj0 >> 4) + t) * N_];

    f32x4 s[4];
    __builtin_amdgcn_s_setprio(1);
#pragma unroll
    for (int t = 0; t < 4; ++t) {
      const int row = t * 16 + li;
      const int rs = row & 7;
      const bf16x8 ka0 = ld_frag(&Kt[cur][row * 64 + ((grp ^ rs) * 8)]);
      const bf16x8 ka1 = ld_frag(&Kt[cur][row * 64 + (((grp + 4) ^ rs) * 8)]);
      f32x4 z = {0.f, 0.f, 0.f, 0.f};
      z = __builtin_amdgcn_mfma_f32_16x16x32_bf16(ka0, bq0, z, 0, 0, 0);
      z = __builtin_amdgcn_mfma_f32_16x16x32_bf16(ka1, bq1, z, 0, 0, 0);
      s[t] = z;
    }
    __builtin_amdgcn_s_setprio(0);

    // mask (scores already scaled via Q); lane holds 16 scores for q = li
    float sv[16];
#pragma unroll
    for (int t = 0; t < 4; ++t) {
      const unsigned mb = (mword[t] >> (grp * 4)) & 0xFu;
#pragma unroll
      for (int j = 0; j < 4; ++j)
        sv[t * 4 + j] = ((mb >> j) & 1u) ? -INFINITY : s[t][j];
    }
    // max3-fusable reduction tree
    const float a0 = fmaxf(fmaxf(sv[0], sv[1]), sv[2]);
    const float a1 = fmaxf(fmaxf(sv[3], sv[4]), sv[5]);
    const float a2 = fmaxf(fmaxf(sv[6], sv[7]), sv[8]);
    const float a3 = fmaxf(fmaxf(sv[9], sv[10]), sv[11]);
    const float a4 = fmaxf(fmaxf(sv[12], sv[13]), sv[14]);
    float rmax = fmaxf(fmaxf(fmaxf(a0, a1), fmaxf(a2, a3)), fmaxf(a4, sv[15]));
    rmax = fmaxf(rmax, __shfl_xor(rmax, 16));
    rmax = fmaxf(rmax, __shfl_xor(rmax, 32));
    // T13 defer-max: rescale only when running max grew by > 8
    if (!__all(rmax <= m + 8.f)) {
      const float mnew = fmaxf(m, rmax);
      const float scal = (m == -INFINITY) ? 0.f : __expf(m - mnew);
      lsum *= scal;
#pragma unroll
      for (int t2 = 0; t2 < 4; ++t2) accO[t2] *= scal;
      m = mnew;
    }
    const float msafe = (m == -INFINITY) ? 0.f : m;
    float psum = 0.f;
    float pv[16];
#pragma unroll
    for (int i = 0; i < 16; ++i) {
      const float e = __expf(sv[i] - msafe);  // exp(-inf)=0 zeroes masked
      pv[i] = e;
      psum += e;
    }
    psum += __shfl_xor(psum, 16);
    psum += __shfl_xor(psum, 32);
    lsum += psum;
    // P -> LDS (bf16 via paired cvt_pk), swizzled
#pragma unroll
    for (int t = 0; t < 4; ++t) {
      bf16x2 plo = { (__bf16)pv[t * 4 + 0], (__bf16)pv[t * 4 + 1] };
      bf16x2 phi = { (__bf16)pv[t * 4 + 2], (__bf16)pv[t * 4 + 3] };
      uint2 pk;
      pk.x = __builtin_bit_cast(unsigned, plo);
      pk.y = __builtin_bit_cast(unsigned, phi);
      *(uint2*)&Pw[prow + ((t * 16 + grp * 4) ^ sw)] = pk;
    }
    // PV: O^T[d][q] += V^T[d][k] * P^T[k][q]
    __builtin_amdgcn_s_setprio(1);
#pragma unroll
    for (int kc = 0; kc < 2; ++kc) {
      const bf16x8 pb = ld_frag(&Pw[prow + ((kc * 32 + grp * 8) ^ sw)]);
#pragma unroll
      for (int t2 = 0; t2 < 4; ++t2) {
        const int row = t2 * 16 + li;
        const bf16x8 va = ld_frag(&Vt[cur][row * 64 + (((kc * 4 + grp) ^ (row & 7)) * 8)]);
        accO[t2] = __builtin_amdgcn_mfma_f32_16x16x32_bf16(va, pb, accO[t2], 0, 0, 0);
      }
    }
    __builtin_amdgcn_s_setprio(0);
    __syncthreads();
    cur ^= 1;
  }
  const float inv = (lsum > 0.f) ? 1.0f / lsum : 0.f;  // all-masked row -> 0
  u16* op = outp + ((size_t)b * N_ + qw + li) * D_ + h * DH_;
#pragma unroll
  for (int t2 = 0; t2 < 4; ++t2) {
    bf16x2 o01 = { (__bf16)(accO[t2][0] * inv), (__bf16)(accO[t2][1] * inv) };
    bf16x2 o23 = { (__bf16)(accO[t2][2] * inv), (__bf16)(accO[t2][3] * inv) };
    uint2 ov;
    ov.x = __builtin_bit_cast(unsigned, o01);
    ov.y = __builtin_bit_cast(unsigned, o23);
    *(uint2*)&op[t2 * 16 + grp * 4] = ov;
  }
}

// ---------------------------------------------------------------------------
// Row LayerNorm over bf16 input (768 = 256*3).
// OUTF32=0: write bf16 ybf; OUTF32=1: write fp32 yf.
template<int OUTF32>
__global__ __launch_bounds__(256)
void ln_kernel(const u16* __restrict__ x, const float* __restrict__ g,
               const float* __restrict__ be, u16* __restrict__ ybf,
               float* __restrict__ yf) {
  const int row = blockIdx.x;
  const int t = threadIdx.x;
  const u16* xr = x + (size_t)row * D_;
  const float v0 = b2f(xr[t]), v1 = b2f(xr[t + 256]), v2 = b2f(xr[t + 512]);
  float s = v0 + v1 + v2;
  float s2 = v0 * v0 + v1 * v1 + v2 * v2;
#pragma unroll
  for (int d = 1; d < 64; d <<= 1) { s += __shfl_xor(s, d); s2 += __shfl_xor(s2, d); }
  __shared__ float red[8];
  const int w = t >> 6;
  if ((t & 63) == 0) { red[w] = s; red[4 + w] = s2; }
  __syncthreads();
  s = red[0] + red[1] + red[2] + red[3];
  s2 = red[4] + red[5] + red[6] + red[7];
  const float mu = s * (1.0f / D_);
  const float var = fmaxf(s2 * (1.0f / D_) - mu * mu, 0.0f);
  const float rstd = rsqrtf(var + 1e-5f);
#pragma unroll
  for (int c = 0; c < 3; ++c) {
    const int idx = t + c * 256;
    const float vv = (c == 0) ? v0 : (c == 1) ? v1 : v2;
    const float o = (vv - mu) * rstd * g[idx] + be[idx];
    if constexpr (OUTF32) yf[(size_t)row * D_ + idx] = o;
    else ybf[(size_t)row * D_ + idx] = f2bu(o);
  }
}

// ---------------------------------------------------------------------------
extern "C" void kernel_launch(void* const* d_in, const int* in_sizes, int n_in,
                              void* d_out, int out_size, void* d_ws, size_t ws_size,
                              hipStream_t stream) {
  (void)in_sizes; (void)n_in; (void)out_size; (void)ws_size;
  const float* nodes = (const float*)d_in[0];
  const float* rel   = (const float*)d_in[1];
  const int*   nmask = (const int*)d_in[2];
  const float* Wq = (const float*)d_in[3];
  const float* bq = (const float*)d_in[4];
  const float* Wk = (const float*)d_in[5];
  const float* bk = (const float*)d_in[6];
  const float* Wv = (const float*)d_in[7];
  const float* bv = (const float*)d_in[8];
  const float* Wo = (const float*)d_in[9];
  const float* bo = (const float*)d_in[10];
  const float* ln1g = (const float*)d_in[11];
  const float* ln1b = (const float*)d_in[12];
  const float* W1 = (const float*)d_in[13];
  const float* b1 = (const float*)d_in[14];
  const float* W2 = (const float*)d_in[15];
  const float* b2 = (const float*)d_in[16];
  const float* ln2g = (const float*)d_in[17];
  const float* ln2b = (const float*)d_in[18];
  float* out = (float*)d_out;

  char* ws = (char*)d_ws;
  u16* Wqk_bf = (u16*)(ws + 0);          // [Wq;Wk] 1536x768
  u16* Wv_bf  = (u16*)(ws + 2359296);
  u16* Wo_bf  = (u16*)(ws + 3538944);
  u16* W1_bf  = (u16*)(ws + 4718592);
  u16* W2_bf  = (u16*)(ws + 7077888);
  u16* Xbf    = (u16*)(ws + 9437184);    // nodes bf16; later reused as attn-out
  u16* qb     = (u16*)(ws + 22020096);   // (b,h,i,dh)
  u16* kb     = (u16*)(ws + 34603008);
  u16* vTb    = (u16*)(ws + 47185920);   // (b,h,dh,i)
  u16* mwb    = (u16*)(ws + 59768832);   // packed mask words; later reused as f1
  u16* prehb  = (u16*)(ws + 22020096);   // bf16, overlays dead qb
  u16* hbf    = (u16*)(ws + 47185920);   // overlays dead vT
  u16* f1b    = (u16*)(ws + 59768832);   // overlays dead mask
  u16* preob  = (u16*)(ws + 84934656);   // bf16
  u16* attno  = Xbf;

  const dim3 blk(256);
  // mask packing + all converts in ONE launch
  CvtArgs ca;
  ca.src[0] = Wq; ca.src[1] = Wk; ca.src[2] = Wv; ca.src[3] = Wo;
  ca.src[4] = W1; ca.src[5] = W2; ca.src[6] = nodes;
  ca.dst[0] = Wqk_bf; ca.dst[1] = Wqk_bf + 768 * 768; ca.dst[2] = Wv_bf;
  ca.dst[3] = Wo_bf; ca.dst[4] = W1_bf; ca.dst[5] = W2_bf; ca.dst[6] = Xbf;
  ca.n4[0] = ca.n4[1] = ca.n4[2] = ca.n4[3] = 147456;
  ca.n4[4] = ca.n4[5] = 294912; ca.n4[6] = 1572864;
  ca.start[0] = 2048; ca.start[1] = 2624; ca.start[2] = 3200; ca.start[3] = 3776;
  ca.start[4] = 4352; ca.start[5] = 5504; ca.start[6] = 6656; ca.start[7] = 12800;
  prep_all<<<12800, blk, 0, stream>>>(ca, rel, nmask, mwb);
  // fused Q,K projection + V projection (independent) in ONE launch
  gemm_qkv<<<1152, blk, 0, stream>>>(Xbf, Wqk_bf, Wv_bf, bq, bk, bv, qb, kb, vTb);
  // attention (1D XCD-chunked grid, 512 threads)
  attn<<<768, dim3(512), 0, stream>>>(qb, kb, vTb, mwb, attno);
  // out-proj + fp32 residual(nodes) -> bf16 pre_h
  gemm_bt<2><<<dim3(6, 64), blk, 0, stream>>>(attno, Wo_bf, bo, nodes, nullptr,
                                              prehb, 768, 768);
  // LN1 -> bf16 h
  ln_kernel<0><<<8192, blk, 0, stream>>>(prehb, ln1g, ln1b, hbf, nullptr);
  // FFN1 + gelu -> bf16
  gemm_bt<3><<<dim3(12, 64), blk, 0, stream>>>(hbf, W1_bf, b1, nullptr, nullptr,
                                               f1b, 1536, 768);
  // FFN2 + bf16 residual(h) -> bf16 pre_out
  gemm_bt<4><<<dim3(6, 64), blk, 0, stream>>>(f1b, W2_bf, b2, nullptr, hbf,
                                              preob, 768, 1536);
  // LN2 -> fp32 output
  ln_kernel<1><<<8192, blk, 0, stream>>>(preob, ln2g, ln2b, nullptr, out);
}